// Round 1
// baseline (173.355 us; speedup 1.0000x reference)
//
#include <hip/hip_runtime.h>
#include <math.h>

#define B_ 8
#define N_ 16384
#define M_ 128
#define C_ 81

// ---------------- Kernel 1: GT prep ----------------
// regression_targets [B,M,4,2] -> hbbA [B*M*5] (x1,y1,x2,y2,area), cv2 [B*M*5]
__global__ void prep_gt(const float* __restrict__ rt,
                        float* __restrict__ hbbA,
                        float* __restrict__ cv2) {
    int g = blockIdx.x * blockDim.x + threadIdx.x;
    if (g >= B_ * M_) return;
    const float* v = rt + (size_t)g * 8;
    float x0 = v[0], y0 = v[1], x1 = v[2], y1 = v[3];
    float x2 = v[4], y2 = v[5], x3 = v[6], y3 = v[7];
    float cx = (x0 + x1 + x2 + x3) * 0.25f;
    float cy = (y0 + y1 + y2 + y3) * 0.25f;
    float e1x = x1 - x0, e1y = y1 - y0;
    float e2x = x3 - x0, e2y = y3 - y0;
    float w = sqrtf(e1x * e1x + e1y * e1y);
    float h = sqrtf(e2x * e2x + e2y * e2y);
    float ang = atan2f(e1y, e1x);
    cv2[g * 5 + 0] = cx;
    cv2[g * 5 + 1] = cy;
    cv2[g * 5 + 2] = w;
    cv2[g * 5 + 3] = h;
    cv2[g * 5 + 4] = ang;
    float mnx = fminf(fminf(x0, x1), fminf(x2, x3));
    float mny = fminf(fminf(y0, y1), fminf(y2, y3));
    float mxx = fmaxf(fmaxf(x0, x1), fmaxf(x2, x3));
    float mxy = fmaxf(fmaxf(y0, y1), fmaxf(y2, y3));
    hbbA[g * 5 + 0] = mnx;
    hbbA[g * 5 + 1] = mny;
    hbbA[g * 5 + 2] = mxx;
    hbbA[g * 5 + 3] = mxy;
    hbbA[g * 5 + 4] = (mxx - mnx) * (mxy - mny);
}

// ---------------- Kernel 2: IoU + argmax ----------------
__global__ void iou_kernel(const float* __restrict__ bp,
                           const float* __restrict__ hbbA,
                           float* __restrict__ miou,
                           int* __restrict__ match) {
    __shared__ float sh[M_ * 5];
    int b = blockIdx.y;
    int n = blockIdx.x * blockDim.x + threadIdx.x;
    for (int t = threadIdx.x; t < M_ * 5; t += blockDim.x)
        sh[t] = hbbA[(size_t)b * M_ * 5 + t];
    __syncthreads();
    const float* p = bp + ((size_t)b * N_ + n) * 5;
    float cx = p[0], cy = p[1], w = p[2], h = p[3], a = p[4];
    float c = cosf(a), s = sinf(a);
    float dx = w * 0.5f, dy = h * 0.5f;
    float ex = fabsf(dx * c) + fabsf(dy * s);
    float ey = fabsf(dx * s) + fabsf(dy * c);
    float ax1 = cx - ex, ay1 = cy - ey, ax2 = cx + ex, ay2 = cy + ey;
    float area_a = (ax2 - ax1) * (ay2 - ay1);
    float best = -1.0f;
    int bm = 0;
    for (int m = 0; m < M_; m++) {
        float bx1 = sh[m * 5 + 0], by1 = sh[m * 5 + 1];
        float bx2 = sh[m * 5 + 2], by2 = sh[m * 5 + 3];
        float ab = sh[m * 5 + 4];
        float lx = fmaxf(ax1, bx1), ly = fmaxf(ay1, by1);
        float rx = fminf(ax2, bx2), ry = fminf(ay2, by2);
        float ww = fmaxf(rx - lx, 0.0f), hh = fmaxf(ry - ly, 0.0f);
        float inter = ww * hh;
        float uni = fmaxf(area_a + ab - inter, 1e-7f);
        float iou = inter / uni;
        if (iou > best) { best = iou; bm = m; }  // first-index tie-break (argmax)
    }
    miou[(size_t)b * N_ + n] = best;
    match[(size_t)b * N_ + n] = bm;
}

// ---------------- block reduce helpers (blockDim = 1024, 16 waves) ----------------
__device__ __forceinline__ unsigned bred_u32(unsigned v, volatile unsigned* lds) {
    for (int o = 32; o > 0; o >>= 1) v += __shfl_down(v, o);
    int lane = threadIdx.x & 63, wv = threadIdx.x >> 6;
    if (lane == 0) lds[wv] = v;
    __syncthreads();
    if (threadIdx.x == 0) {
        unsigned r = 0;
        for (int i = 0; i < 16; i++) r += lds[i];
        lds[16] = r;
    }
    __syncthreads();
    unsigned r = lds[16];
    __syncthreads();
    return r;
}

__device__ __forceinline__ float bred_f32(float v, volatile float* lds) {
    for (int o = 32; o > 0; o >>= 1) v += __shfl_down(v, o);
    int lane = threadIdx.x & 63, wv = threadIdx.x >> 6;
    if (lane == 0) lds[wv] = v;
    __syncthreads();
    if (threadIdx.x == 0) {
        float r = 0.f;
        for (int i = 0; i < 16; i++) r += lds[i];
        lds[16] = r;
    }
    __syncthreads();
    float r = lds[16];
    __syncthreads();
    return r;
}

// ---------------- Kernel 3: exact top-k selection + loss ----------------
// blockIdx.x: 0 = positives (iou desc, idx asc), 1 = negatives (iou asc, idx asc)
// blockIdx.y: image. blockDim = 1024, each thread owns 16 contiguous indices.
__global__ __launch_bounds__(1024)
void select_loss(const float* __restrict__ miou, const int* __restrict__ match,
                 const float* __restrict__ logits, const float* __restrict__ bp,
                 const float* __restrict__ cv2, const int* __restrict__ labels,
                 const int* __restrict__ ns_ptr, float* __restrict__ acc) {
    int type = blockIdx.x;
    int b = blockIdx.y;
    __shared__ unsigned su[17];
    __shared__ unsigned wex[16];
    __shared__ float sf[17];
    __shared__ unsigned sel[256];
    __shared__ unsigned selcnt;
    if (threadIdx.x == 0) selcnt = 0;

    int ns = ns_ptr[0];
    unsigned kpos = (unsigned)(ns / 2);
    unsigned kneg = (unsigned)(ns - ns / 2);
    unsigned ktar = (type == 0) ? kpos : kneg;
    if (ktar > 256u) ktar = 256u;

    const float* mi = miou + (size_t)b * N_;
    unsigned key[16];
    int base = threadIdx.x * 16;
    unsigned vcnt = 0;
#pragma unroll
    for (int j = 0; j < 16; j++) {
        float io = mi[base + j];
        bool pos = (io >= 0.5f);
        unsigned k;
        if (type == 0) {
            if (pos) { unsigned u = __float_as_uint(io) | 0x80000000u; k = ~u; vcnt++; }
            else k = 0xFFFFFFFFu;
        } else {
            if (!pos) { k = __float_as_uint(io) | 0x80000000u; vcnt++; }
            else k = 0xFFFFFFFFu;
        }
        key[j] = k;
    }
    __syncthreads();  // selcnt visible

    unsigned V = bred_u32(vcnt, su);
    unsigned keff = (ktar < V) ? ktar : V;

    // binary search for keff-th smallest key (counting duplicates)
    unsigned lo = 0, hi = 0xFFFFFFFFu;
    while (lo < hi) {
        unsigned mid = lo + ((hi - lo) >> 1);
        unsigned c = 0;
#pragma unroll
        for (int j = 0; j < 16; j++) c += (key[j] <= mid) ? 1u : 0u;
        unsigned tot = bred_u32(c, su);
        if (tot >= keff) hi = mid; else lo = mid + 1;
    }
    unsigned Ckey = lo;

    unsigned cl = 0, ce = 0;
#pragma unroll
    for (int j = 0; j < 16; j++) {
        cl += (key[j] < Ckey) ? 1u : 0u;
        ce += (key[j] == Ckey) ? 1u : 0u;
    }
    unsigned m = bred_u32(cl, su);
    unsigned e = keff - m;  // # of ties at cutoff to take, by ascending index

    // exclusive scan of per-thread tie counts (threads own contiguous chunks)
    unsigned sc = ce;
    for (int o = 1; o < 64; o <<= 1) {
        unsigned t = __shfl_up(sc, o);
        if ((threadIdx.x & 63) >= o) sc += t;
    }
    int wv = threadIdx.x >> 6;
    if ((threadIdx.x & 63) == 63) su[wv] = sc;
    __syncthreads();
    if (threadIdx.x == 0) {
        unsigned run = 0;
        for (int i = 0; i < 16; i++) { wex[i] = run; run += su[i]; }
    }
    __syncthreads();
    unsigned rank = (sc - ce) + wex[wv];

#pragma unroll
    for (int j = 0; j < 16; j++) {
        unsigned k = key[j];
        bool s = false;
        if (k < Ckey) s = true;
        else if (k == Ckey) { s = (rank < e); rank++; }
        if (s) {
            unsigned p = atomicAdd(&selcnt, 1u);
            sel[p] = (unsigned)(base + j);
        }
    }
    __syncthreads();
    unsigned total_sel = selcnt;  // == keff

    float cls_sum = 0.f, reg_sum = 0.f;
    const int bg = C_ - 1;
    for (unsigned sIdx = threadIdx.x; sIdx < total_sel; sIdx += blockDim.x) {
        unsigned i = sel[sIdx];
        const float* lg = logits + ((size_t)b * N_ + i) * C_;
        float mx = -INFINITY;
        for (int c = 0; c < C_; c++) mx = fmaxf(mx, lg[c]);
        float se = 0.f;
        for (int c = 0; c < C_; c++) se += expf(lg[c] - mx);
        float lse = mx + logf(se);
        if (type == 0) {
            int g = match[(size_t)b * N_ + i];
            int tc = labels[b * M_ + g];
            cls_sum += lse - lg[tc];
            const float* pp = bp + ((size_t)b * N_ + i) * 5;
            const float* gg = cv2 + ((size_t)b * M_ + g) * 5;
            for (int d = 0; d < 5; d++) {
                float ad = fabsf(pp[d] - gg[d]);
                reg_sum += (ad < 1.f) ? 0.5f * ad * ad : ad - 0.5f;
            }
        } else {
            cls_sum += lse - lg[bg];
        }
    }
    float cs = bred_f32(cls_sum, sf);
    float rs = bred_f32(reg_sum, sf);
    if (threadIdx.x == 0) {
        if (type == 0) { acc[b * 4 + 0] = cs; acc[b * 4 + 2] = rs; }
        else acc[b * 4 + 1] = cs;
    }
}

// ---------------- Kernel 4: finalize ----------------
__global__ void finalize(const float* __restrict__ acc, float* __restrict__ out) {
    float cls = 0.f, reg = 0.f;
    for (int b = 0; b < B_; b++) {
        cls += acc[b * 4 + 0] + acc[b * 4 + 1];
        reg += acc[b * 4 + 2];
    }
    cls /= (float)B_;
    reg /= (float)B_;
    out[0] = cls + reg;
    out[1] = cls;
    out[2] = reg;
}

extern "C" void kernel_launch(void* const* d_in, const int* in_sizes, int n_in,
                              void* d_out, int out_size, void* d_ws, size_t ws_size,
                              hipStream_t stream) {
    const float* box_pred = (const float*)d_in[0];        // [B,N,5]
    const float* class_pred = (const float*)d_in[1];      // [B,N,C]
    const float* reg_tgt = (const float*)d_in[2];         // [B,M,4,2]
    const int* cls_tgt = (const int*)d_in[3];             // [B,M]
    const int* n_samples = (const int*)d_in[4];           // [1]

    float* ws = (float*)d_ws;
    float* hbbA = ws;                                 // B*M*5
    float* cv2 = hbbA + B_ * M_ * 5;                  // B*M*5
    float* miou = cv2 + B_ * M_ * 5;                  // B*N
    int* match = (int*)(miou + (size_t)B_ * N_);      // B*N
    float* acc = (float*)(match + (size_t)B_ * N_);   // B*4

    prep_gt<<<(B_ * M_ + 255) / 256, 256, 0, stream>>>(reg_tgt, hbbA, cv2);
    iou_kernel<<<dim3(N_ / 256, B_), 256, 0, stream>>>(box_pred, hbbA, miou, match);
    select_loss<<<dim3(2, B_), 1024, 0, stream>>>(miou, match, class_pred, box_pred,
                                                  cv2, cls_tgt, n_samples, acc);
    finalize<<<1, 1, 0, stream>>>(acc, (float*)d_out);
}

// Round 2
// 135.552 us; speedup vs baseline: 1.2789x; 1.2789x over previous
//
#include <hip/hip_runtime.h>
#include <math.h>

#define B_ 8
#define N_ 16384
#define M_ 128
#define C_ 81

// ============ Kernel A: GT hbb prep (in-LDS) + IoU + argmax + out-zeroing ======
__global__ __launch_bounds__(256)
void iou_fused(const float* __restrict__ bp,     // [B,N,5]
               const float* __restrict__ rt,     // [B,M,4,2]
               float* __restrict__ miou,         // [B,N]
               int* __restrict__ match,          // [B,N]
               float* __restrict__ out) {        // [3] zeroed here
    __shared__ float sx1[M_], sy1[M_], sx2[M_], sy2[M_], sab[M_];
    int b = blockIdx.y;
    int n = blockIdx.x * blockDim.x + threadIdx.x;

    if (blockIdx.x == 0 && blockIdx.y == 0 && threadIdx.x < 3)
        out[threadIdx.x] = 0.0f;

    if (threadIdx.x < M_) {
        const float* v = rt + ((size_t)b * M_ + threadIdx.x) * 8;
        float x0 = v[0], y0 = v[1], x1 = v[2], y1 = v[3];
        float x2 = v[4], y2 = v[5], x3 = v[6], y3 = v[7];
        float mnx = fminf(fminf(x0, x1), fminf(x2, x3));
        float mny = fminf(fminf(y0, y1), fminf(y2, y3));
        float mxx = fmaxf(fmaxf(x0, x1), fmaxf(x2, x3));
        float mxy = fmaxf(fmaxf(y0, y1), fmaxf(y2, y3));
        sx1[threadIdx.x] = mnx; sy1[threadIdx.x] = mny;
        sx2[threadIdx.x] = mxx; sy2[threadIdx.x] = mxy;
        sab[threadIdx.x] = (mxx - mnx) * (mxy - mny);
    }
    __syncthreads();

    const float* p = bp + ((size_t)b * N_ + n) * 5;
    float cx = p[0], cy = p[1], w = p[2], h = p[3], a = p[4];
    float c = cosf(a), s = sinf(a);
    float dx = w * 0.5f, dy = h * 0.5f;
    float ex = fabsf(dx * c) + fabsf(dy * s);
    float ey = fabsf(dx * s) + fabsf(dy * c);
    float ax1 = cx - ex, ay1 = cy - ey, ax2 = cx + ex, ay2 = cy + ey;
    float area_a = (ax2 - ax1) * (ay2 - ay1);

    // division-free argmax: track best (inter, uni); init best = -1 (= -1/1)
    float bin = -1.0f, bun = 1.0f;
    int bm = 0;
#pragma unroll 4
    for (int m = 0; m < M_; m++) {
        float lx = fmaxf(ax1, sx1[m]), ly = fmaxf(ay1, sy1[m]);
        float rx = fminf(ax2, sx2[m]), ry = fminf(ay2, sy2[m]);
        float ww = fmaxf(rx - lx, 0.0f), hh = fmaxf(ry - ly, 0.0f);
        float inter = ww * hh;
        float uni = fmaxf(area_a + sab[m] - inter, 1e-7f);
        bool better = inter * bun > bin * uni;   // iou_m > best (uni>0)
        bin = better ? inter : bin;
        bun = better ? uni : bun;
        bm = better ? m : bm;
    }
    miou[(size_t)b * N_ + n] = bin / bun;
    match[(size_t)b * N_ + n] = bm;
}

// ============ block reduce helpers (1024 thr, 16 waves, double-buffered) =======
__device__ __forceinline__ unsigned bredu(unsigned v, unsigned* slot) {
#pragma unroll
    for (int o = 32; o; o >>= 1) v += __shfl_down(v, o);
    if ((threadIdx.x & 63) == 0) slot[threadIdx.x >> 6] = v;
    __syncthreads();
    unsigned r = 0;
#pragma unroll
    for (int i = 0; i < 16; i++) r += slot[i];
    return r;
}

__device__ __forceinline__ float bredf(float v, float* slot) {
#pragma unroll
    for (int o = 32; o; o >>= 1) v += __shfl_down(v, o);
    if ((threadIdx.x & 63) == 0) slot[threadIdx.x >> 6] = v;
    __syncthreads();
    float r = 0.f;
#pragma unroll
    for (int i = 0; i < 16; i++) r += slot[i];
    return r;
}

// ============ Kernel B: exact top-k selection + loss + atomic out ==============
// blockIdx.x: 0 = positives (iou desc, idx asc), 1 = negatives (iou asc, idx asc)
__global__ __launch_bounds__(1024)
void select_loss(const float* __restrict__ miou, const int* __restrict__ match,
                 const float* __restrict__ logits, const float* __restrict__ bp,
                 const float* __restrict__ rt, const int* __restrict__ labels,
                 const int* __restrict__ ns_ptr, float* __restrict__ out) {
    int type = blockIdx.x;
    int b = blockIdx.y;
    __shared__ float s_cv2[5][M_];
    __shared__ unsigned red[32] __attribute__((aligned(16)));
    __shared__ float fred[32] __attribute__((aligned(16)));
    __shared__ unsigned sel[256];
    __shared__ unsigned selcnt;

    int tid = threadIdx.x;
    int lane = tid & 63, wv = tid >> 6;
    if (tid == 0) selcnt = 0;

    // cv2 GT params into LDS (used by positives epilogue)
    if (tid < M_) {
        const float* v = rt + ((size_t)b * M_ + tid) * 8;
        float x0 = v[0], y0 = v[1], x1 = v[2], y1 = v[3];
        float x2 = v[4], y2 = v[5], x3 = v[6], y3 = v[7];
        s_cv2[0][tid] = (x0 + x1 + x2 + x3) * 0.25f;
        s_cv2[1][tid] = (y0 + y1 + y2 + y3) * 0.25f;
        float e1x = x1 - x0, e1y = y1 - y0;
        float e2x = x3 - x0, e2y = y3 - y0;
        s_cv2[2][tid] = sqrtf(e1x * e1x + e1y * e1y);
        s_cv2[3][tid] = sqrtf(e2x * e2x + e2y * e2y);
        s_cv2[4][tid] = atan2f(e1y, e1x);
    }

    int ns = ns_ptr[0];
    unsigned ktar = (type == 0) ? (unsigned)(ns / 2) : (unsigned)(ns - ns / 2);
    if (ktar > 256u) ktar = 256u;

    // load 16 ious (vectorized), build order keys
    const float4* mi4 = (const float4*)(miou + (size_t)b * N_);
    int base = tid * 16;
    unsigned key[16];
    unsigned vcnt = 0;
#pragma unroll
    for (int q = 0; q < 4; q++) {
        float4 v4 = mi4[tid * 4 + q];
        float io[4] = {v4.x, v4.y, v4.z, v4.w};
#pragma unroll
        for (int j = 0; j < 4; j++) {
            bool pos = (io[j] >= 0.5f);
            unsigned k;
            if (type == 0) {
                if (pos) { k = ~(__float_as_uint(io[j]) | 0x80000000u); vcnt++; }
                else k = 0xFFFFFFFFu;
            } else {
                if (!pos) { k = __float_as_uint(io[j]) | 0x80000000u; vcnt++; }
                else k = 0xFFFFFFFFu;
            }
            key[q * 4 + j] = k;
        }
    }
    __syncthreads();  // covers selcnt + s_cv2

    int pc = 0;
    unsigned V = bredu(vcnt, red + 16 * ((pc++) & 1));
    unsigned keff = (ktar < V) ? ktar : V;

    if (keff == V) {
        // fast path: every valid item selected, no ordering needed
#pragma unroll
        for (int j = 0; j < 16; j++) {
            if (key[j] != 0xFFFFFFFFu) {
                unsigned p = atomicAdd(&selcnt, 1u);
                sel[p] = (unsigned)(base + j);
            }
        }
    } else {
        // binary search for keff-th smallest key (with duplicates)
        unsigned lo = 0, hi = 0xFFFFFFFFu;
        while (lo < hi) {
            unsigned mid = lo + ((hi - lo) >> 1);
            unsigned c = 0;
#pragma unroll
            for (int j = 0; j < 16; j++) c += (key[j] <= mid) ? 1u : 0u;
            unsigned tot = bredu(c, red + 16 * ((pc++) & 1));
            if (tot >= keff) hi = mid; else lo = mid + 1;
        }
        unsigned Ckey = lo;

        unsigned cl = 0, ce = 0;
#pragma unroll
        for (int j = 0; j < 16; j++) {
            cl += (key[j] < Ckey) ? 1u : 0u;
            ce += (key[j] == Ckey) ? 1u : 0u;
        }
        unsigned m = bredu(cl, red + 16 * ((pc++) & 1));
        unsigned e = keff - m;  // ties to take, ascending index

        // exclusive rank of this thread's ties (threads own contiguous chunks)
        unsigned sc = ce;
#pragma unroll
        for (int o = 1; o < 64; o <<= 1) {
            unsigned t = __shfl_up(sc, o);
            if (lane >= o) sc += t;
        }
        unsigned* slot = red + 16 * ((pc++) & 1);
        if (lane == 63) slot[wv] = sc;
        __syncthreads();
        unsigned off = 0;
        for (int i = 0; i < wv; i++) off += slot[i];
        unsigned rank = off + sc - ce;

#pragma unroll
        for (int j = 0; j < 16; j++) {
            unsigned k = key[j];
            bool s = false;
            if (k < Ckey) s = true;
            else if (k == Ckey) { s = (rank < e); rank++; }
            if (s) {
                unsigned p = atomicAdd(&selcnt, 1u);
                sel[p] = (unsigned)(base + j);
            }
        }
    }
    __syncthreads();
    unsigned total_sel = selcnt;  // == keff

    // ---- loss: 4 threads per sample ----
    float cls_sum = 0.f, reg_sum = 0.f;
    {
        int g = tid >> 2, q = tid & 3;
        if ((unsigned)g < total_sel) {
            unsigned i = sel[g];
            const float* row = logits + ((size_t)b * N_ + i) * C_;
            int c0 = q * 21;
            int c1 = (c0 + 21 < C_) ? c0 + 21 : C_;
            float mx = -INFINITY;
            for (int c = c0; c < c1; c++) mx = fmaxf(mx, row[c]);
            mx = fmaxf(mx, __shfl_xor(mx, 1));
            mx = fmaxf(mx, __shfl_xor(mx, 2));
            float se = 0.f;
            for (int c = c0; c < c1; c++) se += expf(row[c] - mx);
            se += __shfl_xor(se, 1);
            se += __shfl_xor(se, 2);
            if (q == 0) {
                float lse = mx + logf(se);
                if (type == 0) {
                    int g_gt = match[(size_t)b * N_ + i];
                    int tc = labels[b * M_ + g_gt];
                    cls_sum = lse - row[tc];
                    const float* pp = bp + ((size_t)b * N_ + i) * 5;
#pragma unroll
                    for (int d = 0; d < 5; d++) {
                        float ad = fabsf(pp[d] - s_cv2[d][g_gt]);
                        reg_sum += (ad < 1.f) ? 0.5f * ad * ad : ad - 0.5f;
                    }
                } else {
                    cls_sum = lse - row[C_ - 1];
                }
            }
        }
    }
    float cs = bredf(cls_sum, fred + 16 * 0);
    float rs = bredf(reg_sum, fred + 16 * 1);
    if (tid == 0) {
        const float invB = 1.0f / (float)B_;
        atomicAdd(&out[0], (cs + rs) * invB);
        atomicAdd(&out[1], cs * invB);
        atomicAdd(&out[2], rs * invB);
    }
}

extern "C" void kernel_launch(void* const* d_in, const int* in_sizes, int n_in,
                              void* d_out, int out_size, void* d_ws, size_t ws_size,
                              hipStream_t stream) {
    const float* box_pred = (const float*)d_in[0];     // [B,N,5]
    const float* class_pred = (const float*)d_in[1];   // [B,N,C]
    const float* reg_tgt = (const float*)d_in[2];      // [B,M,4,2]
    const int* cls_tgt = (const int*)d_in[3];          // [B,M]
    const int* n_samples = (const int*)d_in[4];        // [1]

    float* ws = (float*)d_ws;
    float* miou = ws;                                  // B*N (16B aligned)
    int* match = (int*)(miou + (size_t)B_ * N_);       // B*N
    float* out = (float*)d_out;

    iou_fused<<<dim3(N_ / 256, B_), 256, 0, stream>>>(box_pred, reg_tgt, miou, match, out);
    select_loss<<<dim3(2, B_), 1024, 0, stream>>>(miou, match, class_pred, box_pred,
                                                  reg_tgt, cls_tgt, n_samples, out);
}